// Round 17
// baseline (1174.354 us; speedup 1.0000x reference)
//
#include <hip/hip_runtime.h>
#include <hip/hip_bf16.h>
#include <math.h>

typedef __bf16 bf16_t;
typedef __bf16 bf16x8 __attribute__((ext_vector_type(8)));
typedef float  f32x4 __attribute__((ext_vector_type(4)));

// ---------------- problem constants ----------------
constexpr int B_  = 2;
constexpr int CIN = 512, HI = 64, WI = 128;   // conv-transpose input
constexpr int C_  = 256, H_ = 128, W_ = 256;  // residual stream
constexpr int NTOK = B_ * H_ * W_;            // 65536 tokens
constexpr int NWIN = 1024;                    // B * 16 * 32 windows of 8x8

__device__ __forceinline__ unsigned short f2bu(float x) {
    return __builtin_bit_cast(unsigned short, (bf16_t)x);
}

// ---------------- RoPE table: rope[l*32+d]=cos, [2048+l*32+d]=sin (dup halves) --
__global__ __launch_bounds__(256) void k_rope(float* __restrict__ rope) {
    int i = blockIdx.x * 256 + threadIdx.x;
    if (i >= 2048) return;
    int l = i >> 5, d = i & 31;
    int j = d & 15;
    int ly = l >> 3, lx = l & 7;
    float fr = powf(10000.f, -(float)(j & 7) / 8.f);
    float t = (j < 8 ? (float)ly : (float)lx) * fr;
    rope[i]        = cosf(t);
    rope[2048 + i] = sinf(t);
}

// ---------------- multi-segment fp32 -> bf16 convert (weights only) ----------
struct CvtSeg { const float* s; bf16_t* d; unsigned n; };
struct CvtParams { CvtSeg seg[8]; };

__global__ __launch_bounds__(256) void k_cvt(CvtParams P) {
    unsigned base = (blockIdx.x * 256u + threadIdx.x) * 4u;
    for (int s = 0; s < 8; s++) {
        unsigned n = P.seg[s].n;
        if (base < n) {
            float4 v = *(const float4*)(P.seg[s].s + base);
            ushort4 o;
            o.x = f2bu(v.x); o.y = f2bu(v.y); o.z = f2bu(v.z); o.w = f2bu(v.w);
            *(ushort4*)(P.seg[s].d + base) = o;
            return;
        }
        base -= n;
    }
}

// ---------------- x NCHW fp32 -> token-major bf16 xT[(b,u,v)][512] ----------
__global__ __launch_bounds__(256) void k_trx(const float* __restrict__ x,
                                             bf16_t* __restrict__ xT) {
    __shared__ float t[64][65];
    int pos0 = blockIdx.x << 6;
    int ci0  = blockIdx.y << 6;
    int b    = blockIdx.z;
    int tid = threadIdx.x;
    int cpos = tid & 63, rb = tid >> 6;
    const float* src = x + ((size_t)(b * CIN + ci0) << 13) + pos0;
    #pragma unroll
    for (int i = 0; i < 16; i++) {
        int ci = rb + (i << 2);
        t[ci][cpos] = src[((size_t)ci << 13) + cpos];
    }
    __syncthreads();
    int row = tid >> 2, q = tid & 3;
    bf16_t* dst = xT + ((size_t)((b << 13) + pos0 + row) << 9) + ci0 + (q << 4);
    union { uint4 u[2]; unsigned short us[16]; } o;
    #pragma unroll
    for (int e = 0; e < 16; e++)
        o.us[e] = f2bu(t[(q << 4) + e][row]);
    *(uint4*)dst = o.u[0];
    *(uint4*)(dst + 8) = o.u[1];
}

// ---------------- build conv B matrices: B512 (4x128x512) + B2048 (4x128x2048) --
__global__ __launch_bounds__(256) void k_bmat(const float* __restrict__ w2,
                                              const float* __restrict__ w4,
                                              const float* __restrict__ cb2,
                                              const float* __restrict__ cb4,
                                              bf16_t* __restrict__ B512,
                                              bf16_t* __restrict__ B2048,
                                              float* __restrict__ cbias) {
    int idx = blockIdx.x * 256 + threadIdx.x;    // 262144 + 1048576
    if (idx < 262144) {
        int ci = idx & 511, o = (idx >> 9) & 127, p = idx >> 16;
        int rp = p >> 1, rq = p & 1;
        B512[idx] = (bf16_t)w2[((ci * 128 + o) * 2 + rp) * 2 + rq];
        if (idx < 256) cbias[idx] = idx < 128 ? cb2[idx] : cb4[idx - 128];
    } else {
        int i4 = idx - 262144;
        int k = i4 & 2047, o2 = (i4 >> 11) & 127, p = i4 >> 18;
        int ci = k & 511, t = k >> 9;
        int rp = p >> 1, rq = p & 1, a = t >> 1, c = t & 1;
        int kh = 3 - rp - 2 * a, kw = 3 - rq - 2 * c;
        B2048[i4] = (bf16_t)w4[((ci * 128 + o2) * 4 + kh) * 4 + kw];
    }
}

// ---------------- window <-> raw position mapping ----------------
__device__ __forceinline__ int winmap_pos(int idx, int shift) {
    int win = idx >> 6, l = idx & 63;
    int b = win >> 9, wy = (win >> 5) & 15, wx = win & 31;
    int y = ((wy << 3) + (l >> 3) + shift) & 127;
    int x = ((wx << 3) + (l & 7) + shift) & 255;
    return (b << 15) + (y << 8) + x;
}

// fast tanh-gelu: gelu(x) = x - x * rcp(exp(u)+1)
__device__ __forceinline__ float gelu_tanh(float x) {
    float u = 1.5957691216057308f * (x + 0.044715f * x * x * x);
    return x - x * __builtin_amdgcn_rcpf(__expf(u) + 1.f);
}

// XOR-swizzled LDS byte offset for a [128][64] bf16 tile (row stride 128B)
__device__ __forceinline__ int swz(int row, int byteoff) {
    return (row << 7) + (byteoff ^ ((row & 7) << 4));
}

// ---------------- MFMA GEMM body (128-row x 128-col tile): C = A * Bw^T -------
// MODE 0: QKV — store bf16 with RoPE (q scaled, k unscaled) applied in epilogue
// MODE 4: conv scatter — Hres[pos*256 + colbase + n] = acc + bias
template<int MODE>
__device__ __forceinline__ void gemm_body(
    char* smem,
    const bf16_t* __restrict__ A, const bf16_t* __restrict__ Bw,
    const float* __restrict__ bias, bf16_t* __restrict__ Cb,
    float* __restrict__ Hres, const float* __restrict__ rope,
    int K, int ldc, int pshift, int colbase)
{
    char* Asb = smem;
    char* Bsb = smem + 16384;
    const int tid = threadIdx.x;

    int gx = gridDim.x;
    int bx = blockIdx.x, by = blockIdx.y;
    if ((gridDim.y & 7) == 0) {
        int lin = by * gx + bx;
        int grp = gx << 3;
        int q = lin / grp, r = lin - q * grp;
        by = (r & 7) + (q << 3);
        bx = r >> 3;
    }
    const int m0 = by << 7, n0 = bx << 7;

    const int w = tid >> 6, l = tid & 63;
    const int wm = (w >> 1) << 6, wn = (w & 1) << 6;
    const int r16 = l & 15, r4 = l >> 4;
    const int arow = tid >> 3, abyte = (tid & 7) << 4;

    const bf16_t* Ag = A + (size_t)(m0 + arow) * K + ((tid & 7) << 3);
    const bf16_t* Bg = Bw + (size_t)(n0 + arow) * K + ((tid & 7) << 3);

    f32x4 acc[4][4] = {};
    uint4 ra[4], rb[4];
    #pragma unroll
    for (int i = 0; i < 4; i++) {
        ra[i] = *(const uint4*)(Ag + (size_t)(i << 5) * K);
        rb[i] = *(const uint4*)(Bg + (size_t)(i << 5) * K);
    }
    for (int kt = 0; kt < K; kt += 64) {
        __syncthreads();
        #pragma unroll
        for (int i = 0; i < 4; i++) {
            *(uint4*)(Asb + swz(arow + (i << 5), abyte)) = ra[i];
            *(uint4*)(Bsb + swz(arow + (i << 5), abyte)) = rb[i];
        }
        __syncthreads();
        if (kt + 64 < K) {
            #pragma unroll
            for (int i = 0; i < 4; i++) {
                ra[i] = *(const uint4*)(Ag + (size_t)(i << 5) * K + kt + 64);
                rb[i] = *(const uint4*)(Bg + (size_t)(i << 5) * K + kt + 64);
            }
        }
        #pragma unroll
        for (int kk = 0; kk < 2; kk++) {
            bf16x8 af[4], bfr[4];
            #pragma unroll
            for (int f = 0; f < 4; f++)
                af[f] = *(const bf16x8*)(Asb + swz(wm + (f << 4) + r16, (kk << 6) + (r4 << 4)));
            #pragma unroll
            for (int f = 0; f < 4; f++)
                bfr[f] = *(const bf16x8*)(Bsb + swz(wn + (f << 4) + r16, (kk << 6) + (r4 << 4)));
            #pragma unroll
            for (int fm = 0; fm < 4; fm++)
                #pragma unroll
                for (int fn = 0; fn < 4; fn++)
                    acc[fm][fn] = __builtin_amdgcn_mfma_f32_16x16x32_bf16(
                        af[fm], bfr[fn], acc[fm][fn], 0, 0, 0);
        }
    }

    // ---- epilogue: LDS transpose, instruction-contiguous stores ----
    float* Lt = (float*)smem;              // [128][72]
    const int wgrp = wn >> 6;
    #pragma unroll
    for (int p2 = 0; p2 < 2; p2++) {
        __syncthreads();
        if (wgrp == p2) {
            #pragma unroll
            for (int fm = 0; fm < 4; fm++) {
                int lrow = wm + (fm << 4) + (r4 << 2);
                #pragma unroll
                for (int fn = 0; fn < 4; fn++) {
                    f32x4 v = acc[fm][fn];
                    int lcol = (fn << 4) + r16;
                    #pragma unroll
                    for (int j = 0; j < 4; j++)
                        Lt[(lrow + j) * 72 + lcol] = v[j];
                }
            }
        }
        __syncthreads();
        if constexpr (MODE == 0) {
            const int c0 = (tid & 7) << 3;
            const int gcol = n0 + (p2 << 6) + c0;      // 0..768
            const int which = gcol >> 8;               // 0=q 1=k 2=v
            const int dbase = c0 & 31;
            const int pc = c0 ^ 16;
            const float sc = (which == 0) ? 0.17677669529663687f : 1.f;
            #pragma unroll
            for (int rnd = 0; rnd < 4; rnd++) {
                int row = (tid >> 3) + (rnd << 5);
                int lidx = (m0 + row) & 63;
                float vv[8];
                *(float4*)(vv)     = *(const float4*)(Lt + row * 72 + c0);
                *(float4*)(vv + 4) = *(const float4*)(Lt + row * 72 + c0 + 4);
                union { uint4 q; unsigned short us[8]; } o;
                if (which < 2) {
                    float pp[8];
                    *(float4*)(pp)     = *(const float4*)(Lt + row * 72 + pc);
                    *(float4*)(pp + 4) = *(const float4*)(Lt + row * 72 + pc + 4);
                    #pragma unroll
                    for (int i = 0; i < 8; i++) {
                        int d = dbase + i;
                        float cs = rope[lidx * 32 + d];
                        float sn = rope[2048 + lidx * 32 + d];
                        float rot = (d < 16) ? -pp[i] : pp[i];
                        o.us[i] = f2bu((vv[i] * cs + rot * sn) * sc);
                    }
                } else {
                    #pragma unroll
                    for (int i = 0; i < 8; i++) o.us[i] = f2bu(vv[i]);
                }
                *(uint4*)(Cb + (size_t)(m0 + row) * ldc + gcol) = o.q;
            }
        } else {
            const int c0 = (tid & 15) << 2;
            const int gcol = colbase + n0 + (p2 << 6) + c0;
            float bb[4];
            *(float4*)bb = *(const float4*)(bias + gcol);
            const int rp = pshift >> 1, rq = pshift & 1;
            #pragma unroll
            for (int rnd = 0; rnd < 8; rnd++) {
                int row = (tid >> 4) + (rnd << 4);
                float4 v = *(const float4*)(Lt + row * 72 + c0);
                int idx = m0 + row;
                int b = idx >> 13, u = (idx >> 7) & 63, vpos = idx & 127;
                int pos = (b << 15) + (((u << 1) + rp) << 8) + (vpos << 1) + rq;
                float* hp = Hres + ((size_t)pos << 8) + gcol;
                float4 r2;
                r2.x = v.x + bb[0]; r2.y = v.y + bb[1];
                r2.z = v.z + bb[2]; r2.w = v.w + bb[3];
                *(float4*)hp = r2;
            }
        }
    }
}

// conv k=4 halo GEMM body (K=2048, cols 128..255)
__device__ __forceinline__ void conv4_body(
    char* smem, const bf16_t* __restrict__ xT,
    const bf16_t* __restrict__ B2048, const float* __restrict__ cbias,
    float* __restrict__ h_t, int par)
{
    char* Asb = smem;
    char* Bsb = smem + 16384;
    const int tid = threadIdx.x;
    const int rp = par >> 1, rq = par & 1;
    const int m0 = blockIdx.y << 7;

    const int w = tid >> 6, l = tid & 63;
    const int wm = (w >> 1) << 6, wn = (w & 1) << 6;
    const int r16 = l & 15, r4 = l >> 4;
    const int arow = tid >> 3, abyte = (tid & 7) << 4;
    const int klane = (tid & 7) << 3;

    int mr_[4], u_[4], v_[4];
    #pragma unroll
    for (int i = 0; i < 4; i++) {
        mr_[i] = m0 + arow + (i << 5);
        u_[i] = (mr_[i] >> 7) & 63;
        v_[i] = mr_[i] & 127;
    }
    const bf16_t* Bp = B2048 + ((size_t)par << 18);

    auto loadA = [&](int c, uint4* r) {
        int t = c >> 3, ci0 = (c & 7) << 6;
        int dh = rp - 1 + (t >> 1), dw = rq - 1 + (t & 1);
        int off = (dh << 7) + dw;
        #pragma unroll
        for (int i = 0; i < 4; i++) {
            bool ok = ((unsigned)(u_[i] + dh) < (unsigned)HI) &&
                      ((unsigned)(v_[i] + dw) < (unsigned)WI);
            if (ok)
                r[i] = *(const uint4*)(xT + ((size_t)(mr_[i] + off) << 9) + ci0 + klane);
            else
                r[i] = uint4{0, 0, 0, 0};
        }
    };
    auto loadB = [&](int c, uint4* r) {
        #pragma unroll
        for (int i = 0; i < 4; i++)
            r[i] = *(const uint4*)(Bp + ((size_t)(arow + (i << 5)) << 11)
                                   + (c << 6) + klane);
    };

    f32x4 acc[4][4] = {};
    uint4 ra[4], rb[4];
    loadA(0, ra);
    loadB(0, rb);
    for (int c = 0; c < 32; c++) {
        __syncthreads();
        #pragma unroll
        for (int i = 0; i < 4; i++) {
            *(uint4*)(Asb + swz(arow + (i << 5), abyte)) = ra[i];
            *(uint4*)(Bsb + swz(arow + (i << 5), abyte)) = rb[i];
        }
        __syncthreads();
        if (c + 1 < 32) {
            loadA(c + 1, ra);
            loadB(c + 1, rb);
        }
        #pragma unroll
        for (int kk = 0; kk < 2; kk++) {
            bf16x8 af[4], bfr[4];
            #pragma unroll
            for (int f = 0; f < 4; f++)
                af[f] = *(const bf16x8*)(Asb + swz(wm + (f << 4) + r16, (kk << 6) + (r4 << 4)));
            #pragma unroll
            for (int f = 0; f < 4; f++)
                bfr[f] = *(const bf16x8*)(Bsb + swz(wn + (f << 4) + r16, (kk << 6) + (r4 << 4)));
            #pragma unroll
            for (int fm = 0; fm < 4; fm++)
                #pragma unroll
                for (int fn = 0; fn < 4; fn++)
                    acc[fm][fn] = __builtin_amdgcn_mfma_f32_16x16x32_bf16(
                        af[fm], bfr[fn], acc[fm][fn], 0, 0, 0);
        }
    }

    float* Lt = (float*)smem;              // [128][72]
    const int wgrp = wn >> 6;
    #pragma unroll
    for (int p2 = 0; p2 < 2; p2++) {
        __syncthreads();
        if (wgrp == p2) {
            #pragma unroll
            for (int fm = 0; fm < 4; fm++) {
                int lrow = wm + (fm << 4) + (r4 << 2);
                #pragma unroll
                for (int fn = 0; fn < 4; fn++) {
                    f32x4 v = acc[fm][fn];
                    int lcol = (fn << 4) + r16;
                    #pragma unroll
                    for (int j = 0; j < 4; j++)
                        Lt[(lrow + j) * 72 + lcol] = v[j];
                }
            }
        }
        __syncthreads();
        const int c0 = (tid & 15) << 2;
        const int gcol = 128 + (p2 << 6) + c0;
        float bb[4];
        *(float4*)bb = *(const float4*)(cbias + gcol);
        #pragma unroll
        for (int rnd = 0; rnd < 8; rnd++) {
            int row = (tid >> 4) + (rnd << 4);
            float4 v = *(const float4*)(Lt + row * 72 + c0);
            int idx = m0 + row;
            int b = idx >> 13, u = (idx >> 7) & 63, vpos = idx & 127;
            int pos = (b << 15) + (((u << 1) + rp) << 8) + (vpos << 1) + rq;
            float* hp = h_t + ((size_t)pos << 8) + gcol;
            float4 r2;
            r2.x = v.x + bb[0]; r2.y = v.y + bb[1];
            r2.z = v.z + bb[2]; r2.w = v.w + bb[3];
            *(float4*)hp = r2;
        }
    }
}

// QKV GEMM (MODE 0, rope in epilogue)
__global__ __launch_bounds__(256) void k_qkv_gemm(
    const bf16_t* __restrict__ A, const bf16_t* __restrict__ Bw,
    bf16_t* __restrict__ Cb, const float* __restrict__ rope, int K, int ldc) {
    __shared__ char smem[36864];
    gemm_body<0>(smem, A, Bw, nullptr, Cb, nullptr, rope, K, ldc, 0, 0);
}

// combined conv: z<4 -> k2 GEMM parity z (cols 0..127); z>=4 -> k4 halo parity z-4
__global__ __launch_bounds__(256) void k_conv(
    const bf16_t* __restrict__ xT, const bf16_t* __restrict__ B512,
    const bf16_t* __restrict__ B2048, const float* __restrict__ cbias,
    float* __restrict__ h_t) {
    __shared__ char smem[36864];
    int z = blockIdx.z;
    if (z < 4) {
        gemm_body<4>(smem, xT, B512 + ((size_t)z << 16), cbias, nullptr,
                     h_t, nullptr, 512, 0, z, 0);
    } else {
        conv4_body(smem, xT, B2048, cbias, h_t, z - 4);
    }
}

// ---------------- fused MFMA attention + out-proj + residual (round-13) -------
__global__ __launch_bounds__(256) void k_attnp(const bf16_t* __restrict__ qkv,
                                               const bf16_t* __restrict__ wout,
                                               const float* __restrict__ bout,
                                               float* __restrict__ h_t,
                                               int win_base, int shift) {
    __shared__ char smem[18944];
    bf16_t* Vs = (bf16_t*)smem;                          // [32][68]
    const int tid = threadIdx.x;
    const int w = tid >> 6, l = tid & 63;
    const int r16 = l & 15, r4 = l >> 4;
    bf16_t* Ps = (bf16_t*)(smem + 4608) + w * 1152;      // [16][72] per wave
    bf16_t* Os = (bf16_t*)(smem + 13824) + w * 640;      // [16][40] per wave
    const int winl = blockIdx.x;
    const bf16_t* qb = qkv + ((size_t)winl << 6) * 768;

    f32x4 acc[16] = {};
    for (int h = 0; h < 8; h++) {
        const int ho = h << 5;
        __syncthreads();
        {   // stage V^T for this head: Vs[d][tok]
            int tok = tid >> 2, dq = (tid & 3) << 3;
            bf16x8 vv = *(const bf16x8*)(qb + tok * 768 + 512 + ho + dq);
            #pragma unroll
            for (int e = 0; e < 8; e++)
                Vs[(dq + e) * 68 + tok] = vv[e];
        }
        __syncthreads();
        bf16x8 qa = *(const bf16x8*)(qb + (w * 16 + r16) * 768 + ho + r4 * 8);
        f32x4 s[4];
        #pragma unroll
        for (int jt = 0; jt < 4; jt++) {
            f32x4 z = {};
            bf16x8 kb = *(const bf16x8*)(qb + (jt * 16 + r16) * 768 + 256 + ho + r4 * 8);
            s[jt] = __builtin_amdgcn_mfma_f32_16x16x32_bf16(qa, kb, z, 0, 0, 0);
        }
        #pragma unroll
        for (int j = 0; j < 4; j++) {
            float m = fmaxf(fmaxf(s[0][j], s[1][j]), fmaxf(s[2][j], s[3][j]));
            #pragma unroll
            for (int o = 8; o > 0; o >>= 1) m = fmaxf(m, __shfl_xor(m, o));
            float sum = 0.f;
            #pragma unroll
            for (int jt = 0; jt < 4; jt++) { s[jt][j] = __expf(s[jt][j] - m); sum += s[jt][j]; }
            #pragma unroll
            for (int o = 8; o > 0; o >>= 1) sum += __shfl_xor(sum, o);
            float inv = 1.f / sum;
            #pragma unroll
            for (int jt = 0; jt < 4; jt++)
                Ps[(r4 * 4 + j) * 72 + jt * 16 + r16] = (bf16_t)(s[jt][j] * inv);
        }
        f32x4 ov[2] = {};
        #pragma unroll
        for (int kt = 0; kt < 2; kt++) {
            bf16x8 pa = *(const bf16x8*)(Ps + r16 * 72 + kt * 32 + r4 * 8);
            #pragma unroll
            for (int nt = 0; nt < 2; nt++) {
                bf16x8 vb = *(const bf16x8*)(Vs + (nt * 16 + r16) * 68 + kt * 32 + r4 * 8);
                ov[nt] = __builtin_amdgcn_mfma_f32_16x16x32_bf16(pa, vb, ov[nt], 0, 0, 0);
            }
        }
        #pragma unroll
        for (int nt = 0; nt < 2; nt++)
            #pragma unroll
            for (int j = 0; j < 4; j++)
                Os[(r4 * 4 + j) * 40 + nt * 16 + r16] = (bf16_t)ov[nt][j];
        bf16x8 oa = *(const bf16x8*)(Os + r16 * 40 + r4 * 8);
        #pragma unroll
        for (int nt = 0; nt < 16; nt++) {
            bf16x8 wb = *(const bf16x8*)(wout + (nt * 16 + r16) * 256 + ho + r4 * 8);
            acc[nt] = __builtin_amdgcn_mfma_f32_16x16x32_bf16(oa, wb, acc[nt], 0, 0, 0);
        }
    }

    float* Lt = (float*)smem;
    const int gwin = win_base + winl;
    #pragma unroll
    for (int p = 0; p < 4; p++) {
        __syncthreads();
        #pragma unroll
        for (int t2 = 0; t2 < 4; t2++) {
            f32x4 v = acc[p * 4 + t2];
            #pragma unroll
            for (int j = 0; j < 4; j++)
                Lt[(w * 16 + r4 * 4 + j) * 68 + t2 * 16 + r16] = v[j];
        }
        __syncthreads();
        int row = tid >> 2, c0 = (tid & 3) << 4;
        int pos = winmap_pos((gwin << 6) + row, shift);
        float* hp = h_t + ((size_t)pos << 8) + (p << 6) + c0;
        const float* bp = bout + (p << 6) + c0;
        #pragma unroll
        for (int i = 0; i < 4; i++) {
            float4 v = *(const float4*)(Lt + row * 68 + c0 + (i << 2));
            float4 bb = *(const float4*)(bp + (i << 2));
            float4 r = *(const float4*)(hp + (i << 2));
            r.x += v.x + bb.x; r.y += v.y + bb.y;
            r.z += v.z + bb.z; r.w += v.w + bb.w;
            *(float4*)(hp + (i << 2)) = r;
        }
    }
}

// ---------------- fused LN + FF: 32-token blocks, 4 waves, 32 KB LDS ----------
// 5 blocks/CU (20 waves/CU). Per hc2 (256-hidden chunk): 4 sequential 64-col
// GEMM1 passes (acc1[2] reuse) -> gelu -> Hs; barrier; GEMM2 K=256.
__global__ __launch_bounds__(256, 4) void k_ffn(const float* __restrict__ h_in,
                                                const float* __restrict__ gam,
                                                const float* __restrict__ bet,
                                                const bf16_t* __restrict__ w1,
                                                const float* __restrict__ b1,
                                                const bf16_t* __restrict__ w2,
                                                const float* __restrict__ b2,
                                                float* __restrict__ h_t) {
    __shared__ char smem[32768];
    bf16_t* Xs = (bf16_t*)smem;              // [32][256] swizzled, 16 KB
    bf16_t* Hs = (bf16_t*)(smem + 16384);    // [32][256] swizzled, 16 KB
    const int tid = threadIdx.x;
    const int w = tid >> 6, l = tid & 63;
    const int r16 = l & 15, r4 = l >> 4;
    const int tok0 = blockIdx.x << 5;

    // ---- fused channel LayerNorm: wave w handles row (rep*4 + w), 32 rows ----
    {
        const int c = l << 2;
        float4 gv = *(const float4*)(gam + c);
        float4 bv = *(const float4*)(bet + c);
        const float* hsrc = h_in + ((size_t)tok0 << 8);
        #pragma unroll
        for (int rep = 0; rep < 8; rep++) {
            int row = (rep << 2) + w;
            float4 v = *(const float4*)(hsrc + ((size_t)row << 8) + c);
            float s  = v.x + v.y + v.z + v.w;
            float s2 = v.x * v.x + v.y * v.y + v.z * v.z + v.w * v.w;
            #pragma unroll
            for (int o = 32; o > 0; o >>= 1) {
                s += __shfl_xor(s, o); s2 += __shfl_xor(s2, o);
            }
            float mu = s * (1.f / 256.f);
            float rs = rsqrtf(s2 * (1.f / 256.f) - mu * mu + 1e-5f);
            ushort4 o4;
            o4.x = f2bu((v.x - mu) * rs * gv.x + bv.x);
            o4.y = f2bu((v.y - mu) * rs * gv.y + bv.y);
            o4.z = f2bu((v.z - mu) * rs * gv.z + bv.z);
            o4.w = f2bu((v.w - mu) * rs * gv.w + bv.w);
            *(ushort4*)(Xs + (row << 8) + (c ^ ((row & 7) << 3))) = o4;
        }
    }
    __syncthreads();

    f32x4 acc2[2][4] = {};
    #pragma unroll
    for (int hc2 = 0; hc2 < 4; hc2++) {
        // ---- 4 sequential GEMM1 passes; pass p -> hidden cols hc2*256+p*64+w*16
        #pragma unroll
        for (int pass = 0; pass < 4; pass++) {
            f32x4 acc1[2] = {};
            #pragma unroll
            for (int kk = 0; kk < 8; kk++) {
                bf16x8 af[2];
                #pragma unroll
                for (int fm = 0; fm < 2; fm++)
                    af[fm] = *(const bf16x8*)(Xs + (((fm << 4) + r16) << 8)
                              + (((kk << 5) + (r4 << 3)) ^ ((r16 & 7) << 3)));
                int nh = (hc2 << 8) + (pass << 6) + (w << 4) + r16;
                bf16x8 b1f = *(const bf16x8*)(w1 + ((size_t)nh << 8) + (kk << 5) + (r4 << 3));
                #pragma unroll
                for (int fm = 0; fm < 2; fm++)
                    acc1[fm] = __builtin_amdgcn_mfma_f32_16x16x32_bf16(
                        af[fm], b1f, acc1[fm], 0, 0, 0);
            }
            if (hc2 && pass == 0) __syncthreads();   // prev GEMM2 reads done
            {   // gelu + bias -> Hs
                int hcol = (pass << 6) + (w << 4) + r16;      // 0..255
                float bi = b1[(hc2 << 8) + hcol];
                #pragma unroll
                for (int fm = 0; fm < 2; fm++)
                    #pragma unroll
                    for (int j = 0; j < 4; j++) {
                        int row = (fm << 4) + (r4 << 2) + j;
                        Hs[(row << 8) + (hcol ^ ((row & 7) << 3))] =
                            (bf16_t)gelu_tanh(acc1[fm][j] + bi);
                    }
            }
        }
        __syncthreads();
        // ---- GEMM2 partial: wave w -> out cols w*64..+63, K=256
        #pragma unroll
        for (int kk = 0; kk < 8; kk++) {
            bf16x8 a2[2];
            #pragma unroll
            for (int fm = 0; fm < 2; fm++)
                a2[fm] = *(const bf16x8*)(Hs + (((fm << 4) + r16) << 8)
                          + (((kk << 5) + (r4 << 3)) ^ ((r16 & 7) << 3)));
            bf16x8 b2f[4];
            #pragma unroll
            for (int fn = 0; fn < 4; fn++) {
                int nc = (w << 6) + (fn << 4) + r16;
                b2f[fn] = *(const bf16x8*)(w2 + ((size_t)nc << 10) + (hc2 << 8)
                           + (kk << 5) + (r4 << 3));
            }
            #pragma unroll
            for (int fm = 0; fm < 2; fm++)
                #pragma unroll
                for (int fn = 0; fn < 4; fn++)
                    acc2[fm][fn] = __builtin_amdgcn_mfma_f32_16x16x32_bf16(
                        a2[fm], b2f[fn], acc2[fm][fn], 0, 0, 0);
        }
    }

    // ---- epilogue: 2 passes of 128 cols via Lt [32][132], contiguous RMW ----
    float* Lt = (float*)smem;                // 32*132*4 = 16896 B
    #pragma unroll
    for (int p = 0; p < 2; p++) {
        __syncthreads();
        if ((w >> 1) == p) {
            #pragma unroll
            for (int fm = 0; fm < 2; fm++)
                #pragma unroll
                for (int fn = 0; fn < 4; fn++) {
                    f32x4 v = acc2[fm][fn];
                    int col = ((w & 1) << 6) + (fn << 4) + r16;
                    #pragma unroll
                    for (int j = 0; j < 4; j++)
                        Lt[((fm << 4) + (r4 << 2) + j) * 132 + col] = v[j];
                }
        }
        __syncthreads();
        int row = tid >> 3;
        int c0 = (tid & 7) << 4;
        float* hp = h_t + (((size_t)(tok0 + row)) << 8) + (p << 7) + c0;
        const float* bp = b2 + (p << 7) + c0;
        #pragma unroll
        for (int i = 0; i < 4; i++) {
            float4 v = *(const float4*)(Lt + row * 132 + c0 + (i << 2));
            float4 bb = *(const float4*)(bp + (i << 2));
            float4 r = *(const float4*)(hp + (i << 2));
            r.x += v.x + bb.x; r.y += v.y + bb.y;
            r.z += v.z + bb.z; r.w += v.w + bb.w;
            *(float4*)(hp + (i << 2)) = r;
        }
    }
}

// ---------------- channel LayerNorm (attn path, windowed scatter) -------------
__global__ __launch_bounds__(256) void k_ln(const float* __restrict__ h,
                                            const float* __restrict__ g,
                                            const float* __restrict__ bt,
                                            bf16_t* __restrict__ xn,
                                            int windowed, int shift) {
    int tok = (blockIdx.x << 2) + (threadIdx.x >> 6);
    int l = threadIdx.x & 63;
    float4 v = *(const float4*)(h + ((size_t)tok << 8) + (l << 2));
    float s  = v.x + v.y + v.z + v.w;
    float s2 = v.x * v.x + v.y * v.y + v.z * v.z + v.w * v.w;
    #pragma unroll
    for (int o = 32; o > 0; o >>= 1) { s += __shfl_xor(s, o); s2 += __shfl_xor(s2, o); }
    float mu = s * (1.f / 256.f);
    float rs = rsqrtf(s2 * (1.f / 256.f) - mu * mu + 1e-5f);
    int orow = tok;
    if (windowed) {
        int b = tok >> 15, img = tok & 32767;
        int y2 = ((img >> 8) - shift) & 127;
        int x2 = ((img & 255) - shift) & 255;
        orow = (((b << 9) + ((y2 >> 3) << 5) + (x2 >> 3)) << 6) + ((y2 & 7) << 3) + (x2 & 7);
    }
    int c = l << 2;
    float4 gv = *(const float4*)(g + c);
    float4 bv = *(const float4*)(bt + c);
    ushort4 o;
    o.x = f2bu((v.x - mu) * rs * gv.x + bv.x);
    o.y = f2bu((v.y - mu) * rs * gv.y + bv.y);
    o.z = f2bu((v.z - mu) * rs * gv.z + bv.z);
    o.w = f2bu((v.w - mu) * rs * gv.w + bv.w);
    *(ushort4*)(xn + ((size_t)orow << 8) + c) = o;
}

// ---------------- per-batch transpose (path B) ----------------
__global__ __launch_bounds__(256) void k_tr(const float* __restrict__ src,
                                            float* __restrict__ dst) {
    __shared__ float t[64][65];
    int tx = blockIdx.x & 3;
    int ty = blockIdx.x >> 2;
    int tid = threadIdx.x;
    int c = (tx << 6) + (tid & 63), r = tid >> 6;
    #pragma unroll
    for (int i = 0; i < 16; i++)
        t[r + i * 4][tid & 63] = src[(size_t)((ty << 6) + r + i * 4) * 256 + c];
    __syncthreads();
    int tok = (ty << 6) + (tid & 63);
    int c2 = tid >> 6;
    #pragma unroll
    for (int i = 0; i < 16; i++)
        dst[(size_t)((tx << 6) + c2 + i * 4) * 32768 + tok] = t[tid & 63][c2 + i * 4];
}

// ---------------- direct transpose (path A): ht[65536][256] -> out NCHW --------
__global__ __launch_bounds__(256) void k_tr2(const float* __restrict__ ht,
                                             float* __restrict__ out) {
    __shared__ float t[128][65];
    int tk0 = blockIdx.x << 7;
    int c0  = blockIdx.y << 6;
    int tid = threadIdx.x;
    #pragma unroll
    for (int rep = 0; rep < 8; rep++) {
        int idx = rep * 256 + tid;
        int row = idx >> 4, c4 = (idx & 15) << 2;
        float4 v = *(const float4*)(ht + ((size_t)(tk0 + row) << 8) + c0 + c4);
        t[row][c4] = v.x; t[row][c4 + 1] = v.y; t[row][c4 + 2] = v.z; t[row][c4 + 3] = v.w;
    }
    __syncthreads();
    int b = tk0 >> 15, img0 = tk0 & 32767;
    #pragma unroll
    for (int rep = 0; rep < 8; rep++) {
        int idx = rep * 256 + tid;
        int jc = idx & 31, c = idx >> 5;
        float4 v;
        v.x = t[(jc << 2) + 0][c];
        v.y = t[(jc << 2) + 1][c];
        v.z = t[(jc << 2) + 2][c];
        v.w = t[(jc << 2) + 3][c];
        *(float4*)(out + (((size_t)(b << 8) + c0 + c) << 15) + img0 + (jc << 2)) = v;
    }
}

// ---------------- host launch ----------------
extern "C" void kernel_launch(void* const* d_in, const int* in_sizes, int n_in,
                              void* d_out, int out_size, void* d_ws, size_t ws_size,
                              hipStream_t stream) {
    const float* x     = (const float*)d_in[0];
    const float* ct_w2 = (const float*)d_in[1];
    const float* ct_b2 = (const float*)d_in[2];
    const float* ct_w4 = (const float*)d_in[3];
    const float* ct_b4 = (const float*)d_in[4];
    const float* ag[2]  = {(const float*)d_in[5],  (const float*)d_in[10]};
    const float* abt[2] = {(const float*)d_in[6],  (const float*)d_in[11]};
    const float* awq[2] = {(const float*)d_in[7],  (const float*)d_in[12]};
    const float* awo[2] = {(const float*)d_in[8],  (const float*)d_in[13]};
    const float* abo[2] = {(const float*)d_in[9],  (const float*)d_in[14]};
    const float* fg[2]  = {(const float*)d_in[15], (const float*)d_in[21]};
    const float* fbt[2] = {(const float*)d_in[16], (const float*)d_in[22]};
    const float* fw1[2] = {(const float*)d_in[17], (const float*)d_in[23]};
    const float* fb1[2] = {(const float*)d_in[18], (const float*)d_in[24]};
    const float* fw2[2] = {(const float*)d_in[19], (const float*)d_in[25]};
    const float* fb2[2] = {(const float*)d_in[20], (const float*)d_in[26]};

    char* w = (char*)d_ws;
    auto alloc = [&](size_t bytes) {
        char* p = w; w += (bytes + 255) & ~(size_t)255; return p;
    };
    float*  rope  = (float*)alloc(4096 * 4);
    bf16_t* wqkvb[2] = {(bf16_t*)alloc(196608 * 2), (bf16_t*)alloc(196608 * 2)};
    bf16_t* woutb[2] = {(bf16_t*)alloc(65536 * 2),  (bf16_t*)alloc(65536 * 2)};
    bf16_t* fw1b[2]  = {(bf16_t*)alloc(262144 * 2), (bf16_t*)alloc(262144 * 2)};
    bf16_t* fw2b[2]  = {(bf16_t*)alloc(262144 * 2), (bf16_t*)alloc(262144 * 2)};
    bf16_t* B512  = (bf16_t*)alloc((size_t)262144 * 2);
    bf16_t* B2048 = (bf16_t*)alloc((size_t)1048576 * 2);
    float*  cbias = (float*)alloc(256 * 4);
    bf16_t* xT    = (bf16_t*)alloc((size_t)16384 * 512 * 2);
    char*   XN    = alloc(33554432);   // xn (attn) / path-B bounce
    bf16_t* xn = (bf16_t*)XN;

    // residual stream: workspace if it fits (path A), else d_out (path B)
    size_t usedB = (size_t)(w - (char*)d_ws);
    size_t rem = ws_size > usedB ? ws_size - usedB : 0;
    const size_t HT_BYTES = (size_t)NTOK * C_ * 4;      // 67.1 MB
    bool pathA = rem >= HT_BYTES + (size_t)16777216;
    float* h_t = pathA ? (float*)alloc(HT_BYTES) : (float*)d_out;

    usedB = (size_t)(w - (char*)d_ws);
    size_t Sb = ws_size > usedB ? ws_size - usedB : 0;
    if (Sb > (size_t)134217728) Sb = 134217728;
    char* S = w;

    auto p2f = [](size_t v) -> size_t { size_t r = 1; while ((r << 1) <= v) r <<= 1; return r; };
    int CW = (int)(Sb / 98304 >= 1024 ? 1024 : p2f(Sb / 98304));
    if (CW < 16) CW = 16;

    // ---- prep ----
    k_rope<<<8, 256, 0, stream>>>(rope);
    CvtParams P;
    P.seg[0] = { awq[0],  wqkvb[0],  196608 };
    P.seg[1] = { awq[1],  wqkvb[1],  196608 };
    P.seg[2] = { awo[0],  woutb[0],  65536 };
    P.seg[3] = { awo[1],  woutb[1],  65536 };
    P.seg[4] = { fw1[0],  fw1b[0],   262144 };
    P.seg[5] = { fw1[1],  fw1b[1],   262144 };
    P.seg[6] = { fw2[0],  fw2b[0],   262144 };
    P.seg[7] = { fw2[1],  fw2b[1],   262144 };
    unsigned total4 = (196608u * 2 + 65536u * 2 + 262144u * 4) / 4;
    k_cvt<<<(total4 + 255) / 256, 256, 0, stream>>>(P);
    k_bmat<<<5120, 256, 0, stream>>>(ct_w2, ct_w4, ct_b2, ct_b4, B512, B2048, cbias);
    k_trx<<<dim3(128, 8, 2), 256, 0, stream>>>(x, xT);

    // ---- conv-transpose: combined k2+k4 dispatch (z 0..3 = k2, 4..7 = k4) ----
    k_conv<<<dim3(1, 128, 8), 256, 0, stream>>>(xT, B512, B2048, cbias, h_t);

    // ---- two transformer blocks ----
    for (int blk = 0; blk < 2; blk++) {
        int shift = blk ? 4 : 0;
        // windowed attention + residual
        k_ln<<<NTOK / 4, 256, 0, stream>>>(h_t, ag[blk], abt[blk], xn, 1, shift);
        for (int w0 = 0; w0 < NWIN; w0 += CW) {
            bf16_t* qkvc = (bf16_t*)S;
            k_qkv_gemm<<<dim3(6, CW / 2), 256, 0, stream>>>(
                xn + (size_t)w0 * 64 * 256, wqkvb[blk], qkvc, rope, 256, 768);
            k_attnp<<<CW, 256, 0, stream>>>(qkvc, woutb[blk], abo[blk], h_t, w0, shift);
        }
        // fused LN + feed-forward + residual (32-token blocks)
        k_ffn<<<NTOK / 32, 256, 0, stream>>>(h_t, fg[blk], fbt[blk],
                                             fw1b[blk], fb1[blk],
                                             fw2b[blk], fb2[blk], h_t);
    }

    // ---- final: token-major fp32 -> NCHW ----
    if (pathA) {
        k_tr2<<<dim3(512, 4), 256, 0, stream>>>(h_t, (float*)d_out);
    } else {
        for (int b = 0; b < 2; b++) {
            hipMemcpyAsync(XN, h_t + (size_t)b * 32768 * 256, 33554432,
                           hipMemcpyDeviceToDevice, stream);
            k_tr<<<2048, 256, 0, stream>>>((const float*)XN,
                                           (float*)d_out + (size_t)b * 256 * 32768);
        }
    }
}

// Round 18
// 976.327 us; speedup vs baseline: 1.2028x; 1.2028x over previous
//
#include <hip/hip_runtime.h>
#include <hip/hip_bf16.h>
#include <math.h>

typedef __bf16 bf16_t;
typedef __bf16 bf16x8 __attribute__((ext_vector_type(8)));
typedef float  f32x4 __attribute__((ext_vector_type(4)));

// ---------------- problem constants ----------------
constexpr int B_  = 2;
constexpr int CIN = 512, HI = 64, WI = 128;   // conv-transpose input
constexpr int C_  = 256, H_ = 128, W_ = 256;  // residual stream
constexpr int NTOK = B_ * H_ * W_;            // 65536 tokens
constexpr int NWIN = 1024;                    // B * 16 * 32 windows of 8x8

__device__ __forceinline__ unsigned short f2bu(float x) {
    return __builtin_bit_cast(unsigned short, (bf16_t)x);
}

// ---------------- RoPE table: rope[l*32+d]=cos, [2048+l*32+d]=sin (dup halves) --
__global__ __launch_bounds__(256) void k_rope(float* __restrict__ rope) {
    int i = blockIdx.x * 256 + threadIdx.x;
    if (i >= 2048) return;
    int l = i >> 5, d = i & 31;
    int j = d & 15;
    int ly = l >> 3, lx = l & 7;
    float fr = powf(10000.f, -(float)(j & 7) / 8.f);
    float t = (j < 8 ? (float)ly : (float)lx) * fr;
    rope[i]        = cosf(t);
    rope[2048 + i] = sinf(t);
}

// ---------------- multi-segment fp32 -> bf16 convert (weights only) ----------
struct CvtSeg { const float* s; bf16_t* d; unsigned n; };
struct CvtParams { CvtSeg seg[8]; };

__global__ __launch_bounds__(256) void k_cvt(CvtParams P) {
    unsigned base = (blockIdx.x * 256u + threadIdx.x) * 4u;
    for (int s = 0; s < 8; s++) {
        unsigned n = P.seg[s].n;
        if (base < n) {
            float4 v = *(const float4*)(P.seg[s].s + base);
            ushort4 o;
            o.x = f2bu(v.x); o.y = f2bu(v.y); o.z = f2bu(v.z); o.w = f2bu(v.w);
            *(ushort4*)(P.seg[s].d + base) = o;
            return;
        }
        base -= n;
    }
}

// ---------------- x NCHW fp32 -> token-major bf16 xT[(b,u,v)][512] ----------
__global__ __launch_bounds__(256) void k_trx(const float* __restrict__ x,
                                             bf16_t* __restrict__ xT) {
    __shared__ float t[64][65];
    int pos0 = blockIdx.x << 6;
    int ci0  = blockIdx.y << 6;
    int b    = blockIdx.z;
    int tid = threadIdx.x;
    int cpos = tid & 63, rb = tid >> 6;
    const float* src = x + ((size_t)(b * CIN + ci0) << 13) + pos0;
    #pragma unroll
    for (int i = 0; i < 16; i++) {
        int ci = rb + (i << 2);
        t[ci][cpos] = src[((size_t)ci << 13) + cpos];
    }
    __syncthreads();
    int row = tid >> 2, q = tid & 3;
    bf16_t* dst = xT + ((size_t)((b << 13) + pos0 + row) << 9) + ci0 + (q << 4);
    union { uint4 u[2]; unsigned short us[16]; } o;
    #pragma unroll
    for (int e = 0; e < 16; e++)
        o.us[e] = f2bu(t[(q << 4) + e][row]);
    *(uint4*)dst = o.u[0];
    *(uint4*)(dst + 8) = o.u[1];
}

// ---------------- build conv B matrices: B512 (4x128x512) + B2048 (4x128x2048) --
__global__ __launch_bounds__(256) void k_bmat(const float* __restrict__ w2,
                                              const float* __restrict__ w4,
                                              const float* __restrict__ cb2,
                                              const float* __restrict__ cb4,
                                              bf16_t* __restrict__ B512,
                                              bf16_t* __restrict__ B2048,
                                              float* __restrict__ cbias) {
    int idx = blockIdx.x * 256 + threadIdx.x;    // 262144 + 1048576
    if (idx < 262144) {
        int ci = idx & 511, o = (idx >> 9) & 127, p = idx >> 16;
        int rp = p >> 1, rq = p & 1;
        B512[idx] = (bf16_t)w2[((ci * 128 + o) * 2 + rp) * 2 + rq];
        if (idx < 256) cbias[idx] = idx < 128 ? cb2[idx] : cb4[idx - 128];
    } else {
        int i4 = idx - 262144;
        int k = i4 & 2047, o2 = (i4 >> 11) & 127, p = i4 >> 18;
        int ci = k & 511, t = k >> 9;
        int rp = p >> 1, rq = p & 1, a = t >> 1, c = t & 1;
        int kh = 3 - rp - 2 * a, kw = 3 - rq - 2 * c;
        B2048[i4] = (bf16_t)w4[((ci * 128 + o2) * 4 + kh) * 4 + kw];
    }
}

// ---------------- window <-> raw position mapping ----------------
__device__ __forceinline__ int winmap_pos(int idx, int shift) {
    int win = idx >> 6, l = idx & 63;
    int b = win >> 9, wy = (win >> 5) & 15, wx = win & 31;
    int y = ((wy << 3) + (l >> 3) + shift) & 127;
    int x = ((wx << 3) + (l & 7) + shift) & 255;
    return (b << 15) + (y << 8) + x;
}

// fast tanh-gelu: gelu(x) = x - x * rcp(exp(u)+1)
__device__ __forceinline__ float gelu_tanh(float x) {
    float u = 1.5957691216057308f * (x + 0.044715f * x * x * x);
    return x - x * __builtin_amdgcn_rcpf(__expf(u) + 1.f);
}

// XOR-swizzled LDS byte offset for a [128][64] bf16 tile (row stride 128B)
__device__ __forceinline__ int swz(int row, int byteoff) {
    return (row << 7) + (byteoff ^ ((row & 7) << 4));
}

// ---------------- MFMA GEMM body (128-row x 128-col tile): C = A * Bw^T -------
// MODE 0: QKV — store bf16 with RoPE (q scaled, k unscaled) applied in epilogue
// MODE 4: conv scatter — Hres[pos*256 + colbase + n] = acc + bias
template<int MODE>
__device__ __forceinline__ void gemm_body(
    char* smem,
    const bf16_t* __restrict__ A, const bf16_t* __restrict__ Bw,
    const float* __restrict__ bias, bf16_t* __restrict__ Cb,
    float* __restrict__ Hres, const float* __restrict__ rope,
    int K, int ldc, int pshift, int colbase)
{
    char* Asb = smem;
    char* Bsb = smem + 16384;
    const int tid = threadIdx.x;

    int gx = gridDim.x;
    int bx = blockIdx.x, by = blockIdx.y;
    if ((gridDim.y & 7) == 0) {
        int lin = by * gx + bx;
        int grp = gx << 3;
        int q = lin / grp, r = lin - q * grp;
        by = (r & 7) + (q << 3);
        bx = r >> 3;
    }
    const int m0 = by << 7, n0 = bx << 7;

    const int w = tid >> 6, l = tid & 63;
    const int wm = (w >> 1) << 6, wn = (w & 1) << 6;
    const int r16 = l & 15, r4 = l >> 4;
    const int arow = tid >> 3, abyte = (tid & 7) << 4;

    const bf16_t* Ag = A + (size_t)(m0 + arow) * K + ((tid & 7) << 3);
    const bf16_t* Bg = Bw + (size_t)(n0 + arow) * K + ((tid & 7) << 3);

    f32x4 acc[4][4] = {};
    uint4 ra[4], rb[4];
    #pragma unroll
    for (int i = 0; i < 4; i++) {
        ra[i] = *(const uint4*)(Ag + (size_t)(i << 5) * K);
        rb[i] = *(const uint4*)(Bg + (size_t)(i << 5) * K);
    }
    for (int kt = 0; kt < K; kt += 64) {
        __syncthreads();
        #pragma unroll
        for (int i = 0; i < 4; i++) {
            *(uint4*)(Asb + swz(arow + (i << 5), abyte)) = ra[i];
            *(uint4*)(Bsb + swz(arow + (i << 5), abyte)) = rb[i];
        }
        __syncthreads();
        if (kt + 64 < K) {
            #pragma unroll
            for (int i = 0; i < 4; i++) {
                ra[i] = *(const uint4*)(Ag + (size_t)(i << 5) * K + kt + 64);
                rb[i] = *(const uint4*)(Bg + (size_t)(i << 5) * K + kt + 64);
            }
        }
        #pragma unroll
        for (int kk = 0; kk < 2; kk++) {
            bf16x8 af[4], bfr[4];
            #pragma unroll
            for (int f = 0; f < 4; f++)
                af[f] = *(const bf16x8*)(Asb + swz(wm + (f << 4) + r16, (kk << 6) + (r4 << 4)));
            #pragma unroll
            for (int f = 0; f < 4; f++)
                bfr[f] = *(const bf16x8*)(Bsb + swz(wn + (f << 4) + r16, (kk << 6) + (r4 << 4)));
            #pragma unroll
            for (int fm = 0; fm < 4; fm++)
                #pragma unroll
                for (int fn = 0; fn < 4; fn++)
                    acc[fm][fn] = __builtin_amdgcn_mfma_f32_16x16x32_bf16(
                        af[fm], bfr[fn], acc[fm][fn], 0, 0, 0);
        }
    }

    // ---- epilogue: LDS transpose, instruction-contiguous stores ----
    float* Lt = (float*)smem;              // [128][72]
    const int wgrp = wn >> 6;
    #pragma unroll
    for (int p2 = 0; p2 < 2; p2++) {
        __syncthreads();
        if (wgrp == p2) {
            #pragma unroll
            for (int fm = 0; fm < 4; fm++) {
                int lrow = wm + (fm << 4) + (r4 << 2);
                #pragma unroll
                for (int fn = 0; fn < 4; fn++) {
                    f32x4 v = acc[fm][fn];
                    int lcol = (fn << 4) + r16;
                    #pragma unroll
                    for (int j = 0; j < 4; j++)
                        Lt[(lrow + j) * 72 + lcol] = v[j];
                }
            }
        }
        __syncthreads();
        if constexpr (MODE == 0) {
            const int c0 = (tid & 7) << 3;
            const int gcol = n0 + (p2 << 6) + c0;      // 0..768
            const int which = gcol >> 8;               // 0=q 1=k 2=v
            const int dbase = c0 & 31;
            const int pc = c0 ^ 16;
            const float sc = (which == 0) ? 0.17677669529663687f : 1.f;
            #pragma unroll
            for (int rnd = 0; rnd < 4; rnd++) {
                int row = (tid >> 3) + (rnd << 5);
                int lidx = (m0 + row) & 63;
                float vv[8];
                *(float4*)(vv)     = *(const float4*)(Lt + row * 72 + c0);
                *(float4*)(vv + 4) = *(const float4*)(Lt + row * 72 + c0 + 4);
                union { uint4 q; unsigned short us[8]; } o;
                if (which < 2) {
                    float pp[8];
                    *(float4*)(pp)     = *(const float4*)(Lt + row * 72 + pc);
                    *(float4*)(pp + 4) = *(const float4*)(Lt + row * 72 + pc + 4);
                    #pragma unroll
                    for (int i = 0; i < 8; i++) {
                        int d = dbase + i;
                        float cs = rope[lidx * 32 + d];
                        float sn = rope[2048 + lidx * 32 + d];
                        float rot = (d < 16) ? -pp[i] : pp[i];
                        o.us[i] = f2bu((vv[i] * cs + rot * sn) * sc);
                    }
                } else {
                    #pragma unroll
                    for (int i = 0; i < 8; i++) o.us[i] = f2bu(vv[i]);
                }
                *(uint4*)(Cb + (size_t)(m0 + row) * ldc + gcol) = o.q;
            }
        } else {
            const int c0 = (tid & 15) << 2;
            const int gcol = colbase + n0 + (p2 << 6) + c0;
            float bb[4];
            *(float4*)bb = *(const float4*)(bias + gcol);
            const int rp = pshift >> 1, rq = pshift & 1;
            #pragma unroll
            for (int rnd = 0; rnd < 8; rnd++) {
                int row = (tid >> 4) + (rnd << 4);
                float4 v = *(const float4*)(Lt + row * 72 + c0);
                int idx = m0 + row;
                int b = idx >> 13, u = (idx >> 7) & 63, vpos = idx & 127;
                int pos = (b << 15) + (((u << 1) + rp) << 8) + (vpos << 1) + rq;
                float* hp = Hres + ((size_t)pos << 8) + gcol;
                float4 r2;
                r2.x = v.x + bb[0]; r2.y = v.y + bb[1];
                r2.z = v.z + bb[2]; r2.w = v.w + bb[3];
                *(float4*)hp = r2;
            }
        }
    }
}

// conv k=4 halo GEMM body (K=2048, cols 128..255)
__device__ __forceinline__ void conv4_body(
    char* smem, const bf16_t* __restrict__ xT,
    const bf16_t* __restrict__ B2048, const float* __restrict__ cbias,
    float* __restrict__ h_t, int par)
{
    char* Asb = smem;
    char* Bsb = smem + 16384;
    const int tid = threadIdx.x;
    const int rp = par >> 1, rq = par & 1;
    const int m0 = blockIdx.y << 7;

    const int w = tid >> 6, l = tid & 63;
    const int wm = (w >> 1) << 6, wn = (w & 1) << 6;
    const int r16 = l & 15, r4 = l >> 4;
    const int arow = tid >> 3, abyte = (tid & 7) << 4;
    const int klane = (tid & 7) << 3;

    int mr_[4], u_[4], v_[4];
    #pragma unroll
    for (int i = 0; i < 4; i++) {
        mr_[i] = m0 + arow + (i << 5);
        u_[i] = (mr_[i] >> 7) & 63;
        v_[i] = mr_[i] & 127;
    }
    const bf16_t* Bp = B2048 + ((size_t)par << 18);

    auto loadA = [&](int c, uint4* r) {
        int t = c >> 3, ci0 = (c & 7) << 6;
        int dh = rp - 1 + (t >> 1), dw = rq - 1 + (t & 1);
        int off = (dh << 7) + dw;
        #pragma unroll
        for (int i = 0; i < 4; i++) {
            bool ok = ((unsigned)(u_[i] + dh) < (unsigned)HI) &&
                      ((unsigned)(v_[i] + dw) < (unsigned)WI);
            if (ok)
                r[i] = *(const uint4*)(xT + ((size_t)(mr_[i] + off) << 9) + ci0 + klane);
            else
                r[i] = uint4{0, 0, 0, 0};
        }
    };
    auto loadB = [&](int c, uint4* r) {
        #pragma unroll
        for (int i = 0; i < 4; i++)
            r[i] = *(const uint4*)(Bp + ((size_t)(arow + (i << 5)) << 11)
                                   + (c << 6) + klane);
    };

    f32x4 acc[4][4] = {};
    uint4 ra[4], rb[4];
    loadA(0, ra);
    loadB(0, rb);
    for (int c = 0; c < 32; c++) {
        __syncthreads();
        #pragma unroll
        for (int i = 0; i < 4; i++) {
            *(uint4*)(Asb + swz(arow + (i << 5), abyte)) = ra[i];
            *(uint4*)(Bsb + swz(arow + (i << 5), abyte)) = rb[i];
        }
        __syncthreads();
        if (c + 1 < 32) {
            loadA(c + 1, ra);
            loadB(c + 1, rb);
        }
        #pragma unroll
        for (int kk = 0; kk < 2; kk++) {
            bf16x8 af[4], bfr[4];
            #pragma unroll
            for (int f = 0; f < 4; f++)
                af[f] = *(const bf16x8*)(Asb + swz(wm + (f << 4) + r16, (kk << 6) + (r4 << 4)));
            #pragma unroll
            for (int f = 0; f < 4; f++)
                bfr[f] = *(const bf16x8*)(Bsb + swz(wn + (f << 4) + r16, (kk << 6) + (r4 << 4)));
            #pragma unroll
            for (int fm = 0; fm < 4; fm++)
                #pragma unroll
                for (int fn = 0; fn < 4; fn++)
                    acc[fm][fn] = __builtin_amdgcn_mfma_f32_16x16x32_bf16(
                        af[fm], bfr[fn], acc[fm][fn], 0, 0, 0);
        }
    }

    float* Lt = (float*)smem;              // [128][72]
    const int wgrp = wn >> 6;
    #pragma unroll
    for (int p2 = 0; p2 < 2; p2++) {
        __syncthreads();
        if (wgrp == p2) {
            #pragma unroll
            for (int fm = 0; fm < 4; fm++) {
                int lrow = wm + (fm << 4) + (r4 << 2);
                #pragma unroll
                for (int fn = 0; fn < 4; fn++) {
                    f32x4 v = acc[fm][fn];
                    int lcol = (fn << 4) + r16;
                    #pragma unroll
                    for (int j = 0; j < 4; j++)
                        Lt[(lrow + j) * 72 + lcol] = v[j];
                }
            }
        }
        __syncthreads();
        const int c0 = (tid & 15) << 2;
        const int gcol = 128 + (p2 << 6) + c0;
        float bb[4];
        *(float4*)bb = *(const float4*)(cbias + gcol);
        #pragma unroll
        for (int rnd = 0; rnd < 8; rnd++) {
            int row = (tid >> 4) + (rnd << 4);
            float4 v = *(const float4*)(Lt + row * 72 + c0);
            int idx = m0 + row;
            int b = idx >> 13, u = (idx >> 7) & 63, vpos = idx & 127;
            int pos = (b << 15) + (((u << 1) + rp) << 8) + (vpos << 1) + rq;
            float* hp = h_t + ((size_t)pos << 8) + gcol;
            float4 r2;
            r2.x = v.x + bb[0]; r2.y = v.y + bb[1];
            r2.z = v.z + bb[2]; r2.w = v.w + bb[3];
            *(float4*)hp = r2;
        }
    }
}

// QKV GEMM (MODE 0, rope in epilogue)
__global__ __launch_bounds__(256) void k_qkv_gemm(
    const bf16_t* __restrict__ A, const bf16_t* __restrict__ Bw,
    bf16_t* __restrict__ Cb, const float* __restrict__ rope, int K, int ldc) {
    __shared__ char smem[36864];
    gemm_body<0>(smem, A, Bw, nullptr, Cb, nullptr, rope, K, ldc, 0, 0);
}

// combined conv: z<4 -> k2 GEMM parity z (cols 0..127); z>=4 -> k4 halo parity z-4
__global__ __launch_bounds__(256) void k_conv(
    const bf16_t* __restrict__ xT, const bf16_t* __restrict__ B512,
    const bf16_t* __restrict__ B2048, const float* __restrict__ cbias,
    float* __restrict__ h_t) {
    __shared__ char smem[36864];
    int z = blockIdx.z;
    if (z < 4) {
        gemm_body<4>(smem, xT, B512 + ((size_t)z << 16), cbias, nullptr,
                     h_t, nullptr, 512, 0, z, 0);
    } else {
        conv4_body(smem, xT, B2048, cbias, h_t, z - 4);
    }
}

// ---------------- fused MFMA attention + out-proj + residual (round-13) -------
__global__ __launch_bounds__(256) void k_attnp(const bf16_t* __restrict__ qkv,
                                               const bf16_t* __restrict__ wout,
                                               const float* __restrict__ bout,
                                               float* __restrict__ h_t,
                                               int win_base, int shift) {
    __shared__ char smem[18944];
    bf16_t* Vs = (bf16_t*)smem;                          // [32][68]
    const int tid = threadIdx.x;
    const int w = tid >> 6, l = tid & 63;
    const int r16 = l & 15, r4 = l >> 4;
    bf16_t* Ps = (bf16_t*)(smem + 4608) + w * 1152;      // [16][72] per wave
    bf16_t* Os = (bf16_t*)(smem + 13824) + w * 640;      // [16][40] per wave
    const int winl = blockIdx.x;
    const bf16_t* qb = qkv + ((size_t)winl << 6) * 768;

    f32x4 acc[16] = {};
    for (int h = 0; h < 8; h++) {
        const int ho = h << 5;
        __syncthreads();
        {   // stage V^T for this head: Vs[d][tok]
            int tok = tid >> 2, dq = (tid & 3) << 3;
            bf16x8 vv = *(const bf16x8*)(qb + tok * 768 + 512 + ho + dq);
            #pragma unroll
            for (int e = 0; e < 8; e++)
                Vs[(dq + e) * 68 + tok] = vv[e];
        }
        __syncthreads();
        bf16x8 qa = *(const bf16x8*)(qb + (w * 16 + r16) * 768 + ho + r4 * 8);
        f32x4 s[4];
        #pragma unroll
        for (int jt = 0; jt < 4; jt++) {
            f32x4 z = {};
            bf16x8 kb = *(const bf16x8*)(qb + (jt * 16 + r16) * 768 + 256 + ho + r4 * 8);
            s[jt] = __builtin_amdgcn_mfma_f32_16x16x32_bf16(qa, kb, z, 0, 0, 0);
        }
        #pragma unroll
        for (int j = 0; j < 4; j++) {
            float m = fmaxf(fmaxf(s[0][j], s[1][j]), fmaxf(s[2][j], s[3][j]));
            #pragma unroll
            for (int o = 8; o > 0; o >>= 1) m = fmaxf(m, __shfl_xor(m, o));
            float sum = 0.f;
            #pragma unroll
            for (int jt = 0; jt < 4; jt++) { s[jt][j] = __expf(s[jt][j] - m); sum += s[jt][j]; }
            #pragma unroll
            for (int o = 8; o > 0; o >>= 1) sum += __shfl_xor(sum, o);
            float inv = 1.f / sum;
            #pragma unroll
            for (int jt = 0; jt < 4; jt++)
                Ps[(r4 * 4 + j) * 72 + jt * 16 + r16] = (bf16_t)(s[jt][j] * inv);
        }
        f32x4 ov[2] = {};
        #pragma unroll
        for (int kt = 0; kt < 2; kt++) {
            bf16x8 pa = *(const bf16x8*)(Ps + r16 * 72 + kt * 32 + r4 * 8);
            #pragma unroll
            for (int nt = 0; nt < 2; nt++) {
                bf16x8 vb = *(const bf16x8*)(Vs + (nt * 16 + r16) * 68 + kt * 32 + r4 * 8);
                ov[nt] = __builtin_amdgcn_mfma_f32_16x16x32_bf16(pa, vb, ov[nt], 0, 0, 0);
            }
        }
        #pragma unroll
        for (int nt = 0; nt < 2; nt++)
            #pragma unroll
            for (int j = 0; j < 4; j++)
                Os[(r4 * 4 + j) * 40 + nt * 16 + r16] = (bf16_t)ov[nt][j];
        bf16x8 oa = *(const bf16x8*)(Os + r16 * 40 + r4 * 8);
        #pragma unroll
        for (int nt = 0; nt < 16; nt++) {
            bf16x8 wb = *(const bf16x8*)(wout + (nt * 16 + r16) * 256 + ho + r4 * 8);
            acc[nt] = __builtin_amdgcn_mfma_f32_16x16x32_bf16(oa, wb, acc[nt], 0, 0, 0);
        }
    }

    float* Lt = (float*)smem;
    const int gwin = win_base + winl;
    #pragma unroll
    for (int p = 0; p < 4; p++) {
        __syncthreads();
        #pragma unroll
        for (int t2 = 0; t2 < 4; t2++) {
            f32x4 v = acc[p * 4 + t2];
            #pragma unroll
            for (int j = 0; j < 4; j++)
                Lt[(w * 16 + r4 * 4 + j) * 68 + t2 * 16 + r16] = v[j];
        }
        __syncthreads();
        int row = tid >> 2, c0 = (tid & 3) << 4;
        int pos = winmap_pos((gwin << 6) + row, shift);
        float* hp = h_t + ((size_t)pos << 8) + (p << 6) + c0;
        const float* bp = bout + (p << 6) + c0;
        #pragma unroll
        for (int i = 0; i < 4; i++) {
            float4 v = *(const float4*)(Lt + row * 68 + c0 + (i << 2));
            float4 bb = *(const float4*)(bp + (i << 2));
            float4 r = *(const float4*)(hp + (i << 2));
            r.x += v.x + bb.x; r.y += v.y + bb.y;
            r.z += v.z + bb.z; r.w += v.w + bb.w;
            *(float4*)(hp + (i << 2)) = r;
        }
    }
}

// ---------------- fused LN + FF (round-13 proven version, VGPR 64) ----------
__global__ __launch_bounds__(512, 4) void k_ffn(const float* __restrict__ h_in,
                                                const float* __restrict__ gam,
                                                const float* __restrict__ bet,
                                                const bf16_t* __restrict__ w1,
                                                const float* __restrict__ b1,
                                                const bf16_t* __restrict__ w2,
                                                const float* __restrict__ b2,
                                                float* __restrict__ h_t) {
    __shared__ char smem[65536];
    bf16_t* Xs = (bf16_t*)smem;              // [64][256] swizzled, 32 KB
    bf16_t* Hs = (bf16_t*)(smem + 32768);    // [64][256] swizzled, 32 KB
    const int tid = threadIdx.x;
    const int w = tid >> 6, l = tid & 63;
    const int r16 = l & 15, r4 = l >> 4;
    const int tok0 = blockIdx.x << 6;

    {
        const int c = l << 2;
        float4 gv = *(const float4*)(gam + c);
        float4 bv = *(const float4*)(bet + c);
        const float* hsrc = h_in + ((size_t)tok0 << 8);
        #pragma unroll
        for (int rep = 0; rep < 8; rep++) {
            int row = (rep << 3) + w;
            float4 v = *(const float4*)(hsrc + ((size_t)row << 8) + c);
            float s  = v.x + v.y + v.z + v.w;
            float s2 = v.x * v.x + v.y * v.y + v.z * v.z + v.w * v.w;
            #pragma unroll
            for (int o = 32; o > 0; o >>= 1) {
                s += __shfl_xor(s, o); s2 += __shfl_xor(s2, o);
            }
            float mu = s * (1.f / 256.f);
            float rs = rsqrtf(s2 * (1.f / 256.f) - mu * mu + 1e-5f);
            ushort4 o4;
            o4.x = f2bu((v.x - mu) * rs * gv.x + bv.x);
            o4.y = f2bu((v.y - mu) * rs * gv.y + bv.y);
            o4.z = f2bu((v.z - mu) * rs * gv.z + bv.z);
            o4.w = f2bu((v.w - mu) * rs * gv.w + bv.w);
            *(ushort4*)(Xs + (row << 8) + (c ^ ((row & 7) << 3))) = o4;
        }
    }
    __syncthreads();

    f32x4 acc2[4][2] = {};
    #pragma unroll
    for (int hc2 = 0; hc2 < 4; hc2++) {
        f32x4 acc1[4] = {};
        #pragma unroll
        for (int kk = 0; kk < 8; kk++) {
            bf16x8 af[4];
            #pragma unroll
            for (int fm = 0; fm < 4; fm++)
                af[fm] = *(const bf16x8*)(Xs + (((fm << 4) + r16) << 8)
                          + (((kk << 5) + (r4 << 3)) ^ ((r16 & 7) << 3)));
            int nh = (hc2 << 8) + (w << 4) + r16;
            bf16x8 b1f = *(const bf16x8*)(w1 + ((size_t)nh << 8) + (kk << 5) + (r4 << 3));
            #pragma unroll
            for (int fm = 0; fm < 4; fm++)
                acc1[fm] = __builtin_amdgcn_mfma_f32_16x16x32_bf16(
                    af[fm], b1f, acc1[fm], 0, 0, 0);
        }
        if (hc2) __syncthreads();
        {
            int hcol = (w << 4) + r16;
            float bi = b1[(hc2 << 8) + hcol];
            #pragma unroll
            for (int fm = 0; fm < 4; fm++)
                #pragma unroll
                for (int j = 0; j < 4; j++) {
                    int row = (fm << 4) + (r4 << 2) + j;
                    Hs[(row << 8) + (hcol ^ ((row & 7) << 3))] =
                        (bf16_t)gelu_tanh(acc1[fm][j] + bi);
                }
        }
        #pragma unroll
        for (int fm = 0; fm < 4; fm++) acc1[fm] = f32x4{};
        #pragma unroll
        for (int kk = 0; kk < 8; kk++) {
            bf16x8 af[4];
            #pragma unroll
            for (int fm = 0; fm < 4; fm++)
                af[fm] = *(const bf16x8*)(Xs + (((fm << 4) + r16) << 8)
                          + (((kk << 5) + (r4 << 3)) ^ ((r16 & 7) << 3)));
            int nh = (hc2 << 8) + 128 + (w << 4) + r16;
            bf16x8 b1f = *(const bf16x8*)(w1 + ((size_t)nh << 8) + (kk << 5) + (r4 << 3));
            #pragma unroll
            for (int fm = 0; fm < 4; fm++)
                acc1[fm] = __builtin_amdgcn_mfma_f32_16x16x32_bf16(
                    af[fm], b1f, acc1[fm], 0, 0, 0);
        }
        {
            int hcol = 128 + (w << 4) + r16;
            float bi = b1[(hc2 << 8) + hcol];
            #pragma unroll
            for (int fm = 0; fm < 4; fm++)
                #pragma unroll
                for (int j = 0; j < 4; j++) {
                    int row = (fm << 4) + (r4 << 2) + j;
                    Hs[(row << 8) + (hcol ^ ((row & 7) << 3))] =
                        (bf16_t)gelu_tanh(acc1[fm][j] + bi);
                }
        }
        __syncthreads();
        #pragma unroll
        for (int kk = 0; kk < 8; kk++) {
            bf16x8 a2[4];
            #pragma unroll
            for (int fm = 0; fm < 4; fm++)
                a2[fm] = *(const bf16x8*)(Hs + (((fm << 4) + r16) << 8)
                          + (((kk << 5) + (r4 << 3)) ^ ((r16 & 7) << 3)));
            bf16x8 b2f[2];
            #pragma unroll
            for (int fn = 0; fn < 2; fn++) {
                int nc = (w << 5) + (fn << 4) + r16;
                b2f[fn] = *(const bf16x8*)(w2 + ((size_t)nc << 10) + (hc2 << 8)
                           + (kk << 5) + (r4 << 3));
            }
            #pragma unroll
            for (int fm = 0; fm < 4; fm++)
                #pragma unroll
                for (int fn = 0; fn < 2; fn++)
                    acc2[fm][fn] = __builtin_amdgcn_mfma_f32_16x16x32_bf16(
                        a2[fm], b2f[fn], acc2[fm][fn], 0, 0, 0);
        }
    }

    float* Lt = (float*)smem;                // [64][132]
    #pragma unroll
    for (int p = 0; p < 2; p++) {
        __syncthreads();
        if ((w >> 2) == p) {
            #pragma unroll
            for (int fm = 0; fm < 4; fm++)
                #pragma unroll
                for (int fn = 0; fn < 2; fn++) {
                    f32x4 v = acc2[fm][fn];
                    int col = ((w & 3) << 5) + (fn << 4) + r16;
                    #pragma unroll
                    for (int j = 0; j < 4; j++)
                        Lt[((fm << 4) + (r4 << 2) + j) * 132 + col] = v[j];
                }
        }
        __syncthreads();
        int row = tid >> 3;
        int c0 = (tid & 7) << 4;
        float* hp = h_t + (((size_t)(tok0 + row)) << 8) + (p << 7) + c0;
        const float* bp = b2 + (p << 7) + c0;
        #pragma unroll
        for (int i = 0; i < 4; i++) {
            float4 v = *(const float4*)(Lt + row * 132 + c0 + (i << 2));
            float4 bb = *(const float4*)(bp + (i << 2));
            float4 r = *(const float4*)(hp + (i << 2));
            r.x += v.x + bb.x; r.y += v.y + bb.y;
            r.z += v.z + bb.z; r.w += v.w + bb.w;
            *(float4*)(hp + (i << 2)) = r;
        }
    }
}

// ---------------- channel LayerNorm (attn path, windowed scatter) -------------
__global__ __launch_bounds__(256) void k_ln(const float* __restrict__ h,
                                            const float* __restrict__ g,
                                            const float* __restrict__ bt,
                                            bf16_t* __restrict__ xn,
                                            int windowed, int shift) {
    int tok = (blockIdx.x << 2) + (threadIdx.x >> 6);
    int l = threadIdx.x & 63;
    float4 v = *(const float4*)(h + ((size_t)tok << 8) + (l << 2));
    float s  = v.x + v.y + v.z + v.w;
    float s2 = v.x * v.x + v.y * v.y + v.z * v.z + v.w * v.w;
    #pragma unroll
    for (int o = 32; o > 0; o >>= 1) { s += __shfl_xor(s, o); s2 += __shfl_xor(s2, o); }
    float mu = s * (1.f / 256.f);
    float rs = rsqrtf(s2 * (1.f / 256.f) - mu * mu + 1e-5f);
    int orow = tok;
    if (windowed) {
        int b = tok >> 15, img = tok & 32767;
        int y2 = ((img >> 8) - shift) & 127;
        int x2 = ((img & 255) - shift) & 255;
        orow = (((b << 9) + ((y2 >> 3) << 5) + (x2 >> 3)) << 6) + ((y2 & 7) << 3) + (x2 & 7);
    }
    int c = l << 2;
    float4 gv = *(const float4*)(g + c);
    float4 bv = *(const float4*)(bt + c);
    ushort4 o;
    o.x = f2bu((v.x - mu) * rs * gv.x + bv.x);
    o.y = f2bu((v.y - mu) * rs * gv.y + bv.y);
    o.z = f2bu((v.z - mu) * rs * gv.z + bv.z);
    o.w = f2bu((v.w - mu) * rs * gv.w + bv.w);
    *(ushort4*)(xn + ((size_t)orow << 8) + c) = o;
}

// ---------------- per-batch transpose (path B) ----------------
__global__ __launch_bounds__(256) void k_tr(const float* __restrict__ src,
                                            float* __restrict__ dst) {
    __shared__ float t[64][65];
    int tx = blockIdx.x & 3;
    int ty = blockIdx.x >> 2;
    int tid = threadIdx.x;
    int c = (tx << 6) + (tid & 63), r = tid >> 6;
    #pragma unroll
    for (int i = 0; i < 16; i++)
        t[r + i * 4][tid & 63] = src[(size_t)((ty << 6) + r + i * 4) * 256 + c];
    __syncthreads();
    int tok = (ty << 6) + (tid & 63);
    int c2 = tid >> 6;
    #pragma unroll
    for (int i = 0; i < 16; i++)
        dst[(size_t)((tx << 6) + c2 + i * 4) * 32768 + tok] = t[tid & 63][c2 + i * 4];
}

// ---------------- direct transpose (path A): ht[65536][256] -> out NCHW --------
__global__ __launch_bounds__(256) void k_tr2(const float* __restrict__ ht,
                                             float* __restrict__ out) {
    __shared__ float t[128][65];
    int tk0 = blockIdx.x << 7;
    int c0  = blockIdx.y << 6;
    int tid = threadIdx.x;
    #pragma unroll
    for (int rep = 0; rep < 8; rep++) {
        int idx = rep * 256 + tid;
        int row = idx >> 4, c4 = (idx & 15) << 2;
        float4 v = *(const float4*)(ht + ((size_t)(tk0 + row) << 8) + c0 + c4);
        t[row][c4] = v.x; t[row][c4 + 1] = v.y; t[row][c4 + 2] = v.z; t[row][c4 + 3] = v.w;
    }
    __syncthreads();
    int b = tk0 >> 15, img0 = tk0 & 32767;
    #pragma unroll
    for (int rep = 0; rep < 8; rep++) {
        int idx = rep * 256 + tid;
        int jc = idx & 31, c = idx >> 5;
        float4 v;
        v.x = t[(jc << 2) + 0][c];
        v.y = t[(jc << 2) + 1][c];
        v.z = t[(jc << 2) + 2][c];
        v.w = t[(jc << 2) + 3][c];
        *(float4*)(out + (((size_t)(b << 8) + c0 + c) << 15) + img0 + (jc << 2)) = v;
    }
}

// ---------------- host launch ----------------
extern "C" void kernel_launch(void* const* d_in, const int* in_sizes, int n_in,
                              void* d_out, int out_size, void* d_ws, size_t ws_size,
                              hipStream_t stream) {
    const float* x     = (const float*)d_in[0];
    const float* ct_w2 = (const float*)d_in[1];
    const float* ct_b2 = (const float*)d_in[2];
    const float* ct_w4 = (const float*)d_in[3];
    const float* ct_b4 = (const float*)d_in[4];
    const float* ag[2]  = {(const float*)d_in[5],  (const float*)d_in[10]};
    const float* abt[2] = {(const float*)d_in[6],  (const float*)d_in[11]};
    const float* awq[2] = {(const float*)d_in[7],  (const float*)d_in[12]};
    const float* awo[2] = {(const float*)d_in[8],  (const float*)d_in[13]};
    const float* abo[2] = {(const float*)d_in[9],  (const float*)d_in[14]};
    const float* fg[2]  = {(const float*)d_in[15], (const float*)d_in[21]};
    const float* fbt[2] = {(const float*)d_in[16], (const float*)d_in[22]};
    const float* fw1[2] = {(const float*)d_in[17], (const float*)d_in[23]};
    const float* fb1[2] = {(const float*)d_in[18], (const float*)d_in[24]};
    const float* fw2[2] = {(const float*)d_in[19], (const float*)d_in[25]};
    const float* fb2[2] = {(const float*)d_in[20], (const float*)d_in[26]};

    char* w = (char*)d_ws;
    auto alloc = [&](size_t bytes) {
        char* p = w; w += (bytes + 255) & ~(size_t)255; return p;
    };
    float*  rope  = (float*)alloc(4096 * 4);
    bf16_t* wqkvb[2] = {(bf16_t*)alloc(196608 * 2), (bf16_t*)alloc(196608 * 2)};
    bf16_t* woutb[2] = {(bf16_t*)alloc(65536 * 2),  (bf16_t*)alloc(65536 * 2)};
    bf16_t* fw1b[2]  = {(bf16_t*)alloc(262144 * 2), (bf16_t*)alloc(262144 * 2)};
    bf16_t* fw2b[2]  = {(bf16_t*)alloc(262144 * 2), (bf16_t*)alloc(262144 * 2)};
    bf16_t* B512  = (bf16_t*)alloc((size_t)262144 * 2);
    bf16_t* B2048 = (bf16_t*)alloc((size_t)1048576 * 2);
    float*  cbias = (float*)alloc(256 * 4);
    bf16_t* xT    = (bf16_t*)alloc((size_t)16384 * 512 * 2);
    char*   XN    = alloc(33554432);   // xn (attn) / path-B bounce
    bf16_t* xn = (bf16_t*)XN;

    // residual stream: workspace if it fits (path A), else d_out (path B)
    size_t usedB = (size_t)(w - (char*)d_ws);
    size_t rem = ws_size > usedB ? ws_size - usedB : 0;
    const size_t HT_BYTES = (size_t)NTOK * C_ * 4;      // 67.1 MB
    bool pathA = rem >= HT_BYTES + (size_t)16777216;
    float* h_t = pathA ? (float*)alloc(HT_BYTES) : (float*)d_out;

    usedB = (size_t)(w - (char*)d_ws);
    size_t Sb = ws_size > usedB ? ws_size - usedB : 0;
    if (Sb > (size_t)134217728) Sb = 134217728;
    char* S = w;

    auto p2f = [](size_t v) -> size_t { size_t r = 1; while ((r << 1) <= v) r <<= 1; return r; };
    int CW = (int)(Sb / 98304 >= 1024 ? 1024 : p2f(Sb / 98304));
    if (CW < 16) CW = 16;

    // ---- prep ----
    k_rope<<<8, 256, 0, stream>>>(rope);
    CvtParams P;
    P.seg[0] = { awq[0],  wqkvb[0],  196608 };
    P.seg[1] = { awq[1],  wqkvb[1],  196608 };
    P.seg[2] = { awo[0],  woutb[0],  65536 };
    P.seg[3] = { awo[1],  woutb[1],  65536 };
    P.seg[4] = { fw1[0],  fw1b[0],   262144 };
    P.seg[5] = { fw1[1],  fw1b[1],   262144 };
    P.seg[6] = { fw2[0],  fw2b[0],   262144 };
    P.seg[7] = { fw2[1],  fw2b[1],   262144 };
    unsigned total4 = (196608u * 2 + 65536u * 2 + 262144u * 4) / 4;
    k_cvt<<<(total4 + 255) / 256, 256, 0, stream>>>(P);
    k_bmat<<<5120, 256, 0, stream>>>(ct_w2, ct_w4, ct_b2, ct_b4, B512, B2048, cbias);
    k_trx<<<dim3(128, 8, 2), 256, 0, stream>>>(x, xT);

    // ---- conv-transpose: combined k2+k4 dispatch (z 0..3 = k2, 4..7 = k4) ----
    k_conv<<<dim3(1, 128, 8), 256, 0, stream>>>(xT, B512, B2048, cbias, h_t);

    // ---- two transformer blocks ----
    for (int blk = 0; blk < 2; blk++) {
        int shift = blk ? 4 : 0;
        // windowed attention + residual
        k_ln<<<NTOK / 4, 256, 0, stream>>>(h_t, ag[blk], abt[blk], xn, 1, shift);
        for (int w0 = 0; w0 < NWIN; w0 += CW) {
            bf16_t* qkvc = (bf16_t*)S;
            k_qkv_gemm<<<dim3(6, CW / 2), 256, 0, stream>>>(
                xn + (size_t)w0 * 64 * 256, wqkvb[blk], qkvc, rope, 256, 768);
            k_attnp<<<CW, 256, 0, stream>>>(qkvc, woutb[blk], abo[blk], h_t, w0, shift);
        }
        // fused LN + feed-forward + residual
        k_ffn<<<NTOK / 64, 512, 0, stream>>>(h_t, fg[blk], fbt[blk],
                                             fw1b[blk], fb1[blk],
                                             fw2b[blk], fb2[blk], h_t);
    }

    // ---- final: token-major fp32 -> NCHW ----
    if (pathA) {
        k_tr2<<<dim3(512, 4), 256, 0, stream>>>(h_t, (float*)d_out);
    } else {
        for (int b = 0; b < 2; b++) {
            hipMemcpyAsync(XN, h_t + (size_t)b * 32768 * 256, 33554432,
                           hipMemcpyDeviceToDevice, stream);
            k_tr<<<2048, 256, 0, stream>>>((const float*)XN,
                                           (float*)d_out + (size_t)b * 256 * 32768);
        }
    }
}